// Round 2
// baseline (131.192 us; speedup 1.0000x reference)
//
#include <hip/hip_runtime.h>
#include <math.h>

#define BATCH 2
#define NPTS  1024
#define NC    32
#define DIN   8
#define DOUT  8
#define TA    2            // a's per thread
#define BCHUNK 8           // b's per block
#define PCHUNK (NPTS / BCHUNK)   // 128 b-chunks
// grid = BATCH * (NPTS/(256*TA)) * PCHUNK = 2 * 2 * 128 = 512 blocks

// ---------------------------------------------------------------------------
// Fused kernel:
//  stage 1: block computes g[b,c,i] = sum_j W[c,i,j]*feat[z,b,j] for its
//           b-chunk into LDS (thread t <-> (c,i) = (t>>3, t&7); 8 fma per b).
//  stage 2: thread t handles a = atile*512 + t and a+256; loops over the 8
//           staged b's x 32 centers, reading g via broadcast ds_read (free of
//           bank conflicts), accumulating 16 fp32 results in registers.
//  epilogue: atomicAdd into out (cross-chunk reduction).
// ---------------------------------------------------------------------------
__global__ __launch_bounds__(256) void fused_conv(
        const float* __restrict__ feat,
        const float* __restrict__ geo,
        const float* __restrict__ W,
        const int*   __restrict__ n_norm,
        float*       __restrict__ out) {
    __shared__ float g_lds[BCHUNK * NC * DOUT];   // 8 KB
    __shared__ float bgeo[BCHUNK][4];             // padded to 4

    const int t     = threadIdx.x;
    const int bid   = blockIdx.x;
    const int chunk = bid & (PCHUNK - 1);
    const int rest  = bid >> 7;                   // log2(PCHUNK)
    const int atile = rest & 1;
    const int z     = rest >> 1;

    const int b0 = chunk * BCHUNK;
    const float* geoz  = geo  + (size_t)z * NPTS * 3;
    const float* featz = feat + (size_t)z * NPTS * DIN;

    // ---- stage g chunk into LDS ----
    // thread t owns (c,i): W row = W + t*8
    const float4 w0 = *(const float4*)(W + t * 8);
    const float4 w1 = *(const float4*)(W + t * 8 + 4);
#pragma unroll
    for (int b = 0; b < BCHUNK; ++b) {
        const float* f = featz + (b0 + b) * DIN;   // wave-uniform -> s_load
        float s = fmaf(w0.x, f[0],
                  fmaf(w0.y, f[1],
                  fmaf(w0.z, f[2],
                  fmaf(w0.w, f[3],
                  fmaf(w1.x, f[4],
                  fmaf(w1.y, f[5],
                  fmaf(w1.z, f[6],
                         w1.w * f[7])))))));
        g_lds[b * (NC * DOUT) + t] = s;
    }
    if (t < BCHUNK) {
        bgeo[t][0] = geoz[(b0 + t) * 3 + 0];
        bgeo[t][1] = geoz[(b0 + t) * 3 + 1];
        bgeo[t][2] = geoz[(b0 + t) * 3 + 2];
    }
    __syncthreads();

    // ---- main loop ----
    const int a0 = atile * 512 + t;               // and a0 + 256
    const float ax0 = geoz[a0 * 3 + 0];
    const float ay0 = geoz[a0 * 3 + 1];
    const float az0 = geoz[a0 * 3 + 2];
    const float ax1 = geoz[(a0 + 256) * 3 + 0];
    const float ay1 = geoz[(a0 + 256) * 3 + 1];
    const float az1 = geoz[(a0 + 256) * 3 + 2];

    const float invw = (float)(NC - 1) / 3.5f;    // 1/width

    float acc0[DOUT], acc1[DOUT];
#pragma unroll
    for (int i = 0; i < DOUT; ++i) { acc0[i] = 0.f; acc1[i] = 0.f; }

#pragma unroll 1
    for (int b = 0; b < BCHUNK; ++b) {
        const float bx = bgeo[b][0];
        const float by = bgeo[b][1];
        const float bz = bgeo[b][2];
        float dx0 = bx - ax0, dy0 = by - ay0, dz0 = bz - az0;
        float dx1 = bx - ax1, dy1 = by - ay1, dz1 = bz - az1;
        float u0 = sqrtf(fmaf(dx0, dx0, fmaf(dy0, dy0, fmaf(dz0, dz0, 1e-12f)))) * invw;
        float u1 = sqrtf(fmaf(dx1, dx1, fmaf(dy1, dy1, fmaf(dz1, dz1, 1e-12f)))) * invw;
        const float* gb = &g_lds[b * (NC * DOUT)];
#pragma unroll
        for (int c = 0; c < NC; ++c) {
            float t0 = u0 - (float)c;
            float t1 = u1 - (float)c;
            float e0 = __expf(-(t0 * t0));
            float e1 = __expf(-(t1 * t1));
#pragma unroll
            for (int i = 0; i < DOUT; ++i) {
                float gv = gb[c * DOUT + i];       // broadcast ds_read
                acc0[i] = fmaf(e0, gv, acc0[i]);
                acc1[i] = fmaf(e1, gv, acc1[i]);
            }
        }
    }

    // ---- epilogue ----
    const float scale = 1.0f / sqrtf((float)n_norm[0]);
    float* o0 = out + ((size_t)(z * NPTS + a0)) * DOUT;
    float* o1 = out + ((size_t)(z * NPTS + a0 + 256)) * DOUT;
#pragma unroll
    for (int i = 0; i < DOUT; ++i) {
        atomicAdd(&o0[i], acc0[i] * scale);
        atomicAdd(&o1[i], acc1[i] * scale);
    }
}

// ---------------------------------------------------------------------------
extern "C" void kernel_launch(void* const* d_in, const int* in_sizes, int n_in,
                              void* d_out, int out_size, void* d_ws, size_t ws_size,
                              hipStream_t stream) {
    const float* feat   = (const float*)d_in[0];   // [2,1024,8]
    const float* geo    = (const float*)d_in[1];   // [2,1024,3]
    const float* W      = (const float*)d_in[2];   // [32,8,8]
    const int*   n_norm = (const int*)  d_in[3];   // scalar 1024
    float* out = (float*)d_out;                    // [2,1024,8]

    // out is re-poisoned before every launch -> zero it (atomic accumulate).
    hipMemsetAsync(d_out, 0, (size_t)out_size * sizeof(float), stream);

    const int grid = BATCH * (NPTS / (256 * TA)) * PCHUNK;   // 512
    fused_conv<<<grid, 256, 0, stream>>>(feat, geo, W, n_norm, out);
}

// Round 3
// 93.517 us; speedup vs baseline: 1.4029x; 1.4029x over previous
//
#include <hip/hip_runtime.h>
#include <math.h>

#define BATCH 2
#define NPTS  1024
#define NC    32
#define DIN   8
#define DOUT  8
#define TA    2            // a's per thread
#define OUT_ELEMS (BATCH * NPTS * DOUT)   // 16384

// ---------------------------------------------------------------------------
// Kernel 1: per-(z, atile, chunk) block computes partial sums over its BCHUNK
// b's and writes them to a PRIVATE coalesced slice of the workspace.
// No atomics anywhere (Round-2 counters: WRITE_SIZE == 32B * n_atomics, all
// 2M atomics hitting 1024 cache lines -> serialized RMW was the bottleneck).
// ---------------------------------------------------------------------------
template <int BCHUNK>
__global__ __launch_bounds__(256) void conv_partial(
        const float* __restrict__ feat,
        const float* __restrict__ geo,
        const float* __restrict__ W,
        float*       __restrict__ partial) {   // [NCHUNK][BATCH][NPTS][DOUT]
    constexpr int NCHUNK = NPTS / BCHUNK;
    __shared__ float g_lds[BCHUNK * NC * DOUT];
    __shared__ float bgeo[BCHUNK][4];

    const int t     = threadIdx.x;
    const int bid   = blockIdx.x;
    const int chunk = bid % NCHUNK;
    const int rest  = bid / NCHUNK;
    const int atile = rest & 1;               // 2 atiles per z (TA=2)
    const int z     = rest >> 1;

    const int b0 = chunk * BCHUNK;
    const float* geoz  = geo  + (size_t)z * NPTS * 3;
    const float* featz = feat + (size_t)z * NPTS * DIN;

    // ---- stage g[b,c,i] for this chunk into LDS; thread t owns (c,i) ----
    const float4 w0 = *(const float4*)(W + t * 8);
    const float4 w1 = *(const float4*)(W + t * 8 + 4);
#pragma unroll
    for (int b = 0; b < BCHUNK; ++b) {
        const float* f = featz + (b0 + b) * DIN;   // wave-uniform -> s_load
        float s = fmaf(w0.x, f[0],
                  fmaf(w0.y, f[1],
                  fmaf(w0.z, f[2],
                  fmaf(w0.w, f[3],
                  fmaf(w1.x, f[4],
                  fmaf(w1.y, f[5],
                  fmaf(w1.z, f[6],
                         w1.w * f[7])))))));
        g_lds[b * (NC * DOUT) + t] = s;
    }
    if (t < BCHUNK) {
        bgeo[t][0] = geoz[(b0 + t) * 3 + 0];
        bgeo[t][1] = geoz[(b0 + t) * 3 + 1];
        bgeo[t][2] = geoz[(b0 + t) * 3 + 2];
    }
    __syncthreads();

    // ---- main loop: thread t handles a0 = atile*512 + t and a0+256 ----
    const int a0 = atile * 512 + t;
    const float ax0 = geoz[a0 * 3 + 0];
    const float ay0 = geoz[a0 * 3 + 1];
    const float az0 = geoz[a0 * 3 + 2];
    const float ax1 = geoz[(a0 + 256) * 3 + 0];
    const float ay1 = geoz[(a0 + 256) * 3 + 1];
    const float az1 = geoz[(a0 + 256) * 3 + 2];

    const float invw = (float)(NC - 1) / 3.5f;

    float acc0[DOUT], acc1[DOUT];
#pragma unroll
    for (int i = 0; i < DOUT; ++i) { acc0[i] = 0.f; acc1[i] = 0.f; }

#pragma unroll 1
    for (int b = 0; b < BCHUNK; ++b) {
        const float bx = bgeo[b][0];
        const float by = bgeo[b][1];
        const float bz = bgeo[b][2];
        float dx0 = bx - ax0, dy0 = by - ay0, dz0 = bz - az0;
        float dx1 = bx - ax1, dy1 = by - ay1, dz1 = bz - az1;
        float u0 = sqrtf(fmaf(dx0, dx0, fmaf(dy0, dy0, fmaf(dz0, dz0, 1e-12f)))) * invw;
        float u1 = sqrtf(fmaf(dx1, dx1, fmaf(dy1, dy1, fmaf(dz1, dz1, 1e-12f)))) * invw;
        const float* gb = &g_lds[b * (NC * DOUT)];
#pragma unroll
        for (int c = 0; c < NC; ++c) {
            float t0 = u0 - (float)c;
            float t1 = u1 - (float)c;
            float e0 = __expf(-(t0 * t0));
            float e1 = __expf(-(t1 * t1));
#pragma unroll
            for (int i = 0; i < DOUT; ++i) {
                float gv = gb[c * DOUT + i];       // broadcast ds_read, 0 conflicts
                acc0[i] = fmaf(e0, gv, acc0[i]);
                acc1[i] = fmaf(e1, gv, acc1[i]);
            }
        }
    }

    // ---- epilogue: private coalesced float4 stores, no atomics ----
    float* p0 = partial + (size_t)chunk * OUT_ELEMS + ((size_t)(z * NPTS + a0)) * DOUT;
    float* p1 = p0 + 256 * DOUT;
    ((float4*)p0)[0] = make_float4(acc0[0], acc0[1], acc0[2], acc0[3]);
    ((float4*)p0)[1] = make_float4(acc0[4], acc0[5], acc0[6], acc0[7]);
    ((float4*)p1)[0] = make_float4(acc1[0], acc1[1], acc1[2], acc1[3]);
    ((float4*)p1)[1] = make_float4(acc1[4], acc1[5], acc1[6], acc1[7]);
}

// ---------------------------------------------------------------------------
// Kernel 2: out[e] = scale * sum_chunk partial[chunk][e]. Coalesced strided
// reads (consecutive lanes -> consecutive addresses), LLC-resident.
// ---------------------------------------------------------------------------
__global__ __launch_bounds__(128) void reduce_partials(
        const float* __restrict__ partial,
        const int*   __restrict__ n_norm,
        float*       __restrict__ out,
        int nchunk) {
    int e = blockIdx.x * blockDim.x + threadIdx.x;
    if (e >= OUT_ELEMS) return;
    float s = 0.f;
#pragma unroll 8
    for (int c = 0; c < nchunk; ++c)
        s += partial[(size_t)c * OUT_ELEMS + e];
    out[e] = s * (1.0f / sqrtf((float)n_norm[0]));
}

// ---------------------------------------------------------------------------
extern "C" void kernel_launch(void* const* d_in, const int* in_sizes, int n_in,
                              void* d_out, int out_size, void* d_ws, size_t ws_size,
                              hipStream_t stream) {
    const float* feat   = (const float*)d_in[0];   // [2,1024,8]
    const float* geo    = (const float*)d_in[1];   // [2,1024,3]
    const float* W      = (const float*)d_in[2];   // [32,8,8]
    const int*   n_norm = (const int*)  d_in[3];   // scalar 1024
    float* out     = (float*)d_out;                // [2,1024,8]
    float* partial = (float*)d_ws;

    const size_t need128 = (size_t)128 * OUT_ELEMS * sizeof(float);  // 8 MB
    if (ws_size >= need128) {
        constexpr int BCHUNK = 8, NCHUNK = NPTS / BCHUNK;            // 128 chunks
        const int grid = BATCH * 2 * NCHUNK;                         // 512 blocks
        conv_partial<BCHUNK><<<grid, 256, 0, stream>>>(feat, geo, W, partial);
        reduce_partials<<<(OUT_ELEMS + 127) / 128, 128, 0, stream>>>(
            partial, n_norm, out, NCHUNK);
    } else {
        constexpr int BCHUNK = 32, NCHUNK = NPTS / BCHUNK;           // 32 chunks, 2 MB
        const int grid = BATCH * 2 * NCHUNK;                         // 128 blocks
        conv_partial<BCHUNK><<<grid, 256, 0, stream>>>(feat, geo, W, partial);
        reduce_partials<<<(OUT_ELEMS + 127) / 128, 128, 0, stream>>>(
            partial, n_norm, out, NCHUNK);
    }
}